// Round 8
// baseline (220.445 us; speedup 1.0000x reference)
//
#include <hip/hip_runtime.h>

// Problem constants (B=4, N=512, D_in=512, D_out=256), fp32 in/out.
constexpr int Bq   = 4;
constexpr int Nq   = 512;
constexpr int DIN  = 512;
constexpr int DOUT = 256;

__device__ __forceinline__ void fma4(float4& acc, const float s, const float4 v) {
    acc.x = __builtin_fmaf(s, v.x, acc.x);
    acc.y = __builtin_fmaf(s, v.y, acc.y);
    acc.z = __builtin_fmaf(s, v.z, acc.z);
    acc.w = __builtin_fmaf(s, v.w, acc.w);
}

// ---------------------------------------------------------------------------
// K0: WT[k][o] = W[o][k]  (512x256 <- 256x512), LDS tile transpose.
// ---------------------------------------------------------------------------
__global__ __launch_bounds__(256) void k0_wt(const float* __restrict__ W,
                                             float* __restrict__ WT) {
    __shared__ float tile[32][33];
    const int k0 = blockIdx.x * 32;
    const int o0 = blockIdx.y * 32;
    const int tx = threadIdx.x;       // 32
    const int ty = threadIdx.y;       // 8
#pragma unroll
    for (int j = 0; j < 4; ++j)
        tile[ty + 8 * j][tx] = W[(o0 + ty + 8 * j) * DIN + k0 + tx];
    __syncthreads();
#pragma unroll
    for (int j = 0; j < 4; ++j)
        WT[(k0 + ty + 8 * j) * DOUT + o0 + tx] = tile[tx][ty + 8 * j];
}

// ---------------------------------------------------------------------------
// K1: Wh = H @ WT (+ WhT + r = Wh.a). Block = (b, 8 n-rows), 512 threads.
// Thread = (k-phase p = wave, o-quad oq). WT float4 loaded ONCE per block
// element (coalesced 1KB/wave, 8-deep dbuf); H rows staged in LDS once and
// read as ds_read_b128 BROADCASTS (uniform addr -> conflict-free, LDS pipe,
// no VMEM latency in loop). Phase partials reduced via 64 KB LDS, 1 barrier.
// ---------------------------------------------------------------------------
__global__ __launch_bounds__(512, 4) void k1_wh(const float* __restrict__ H,
                                                const float* __restrict__ WT,
                                                const float* __restrict__ a,
                                                float* __restrict__ Wh,
                                                float* __restrict__ WhT,
                                                float* __restrict__ r) {
    const int t   = threadIdx.x;
    const int blk = blockIdx.x;           // 256
    const int b   = blk & 3;              // XCD-swizzled batch
    const int n0  = (blk >> 2) << 3;
    const int p   = __builtin_amdgcn_readfirstlane(t >> 6);  // k-phase 0..7
    const int oq  = t & 63;               // o-quad

    __shared__ float  sH[8 * 512];        // 16 KB (H rows)
    __shared__ float4 sPart[8][8][64];    // 64 KB (phase partials)

    {   // stage H rows once (coalesced)
        const float4* src = (const float4*)(H + ((size_t)(b * Nq) + n0) * DIN);
        float4* dst = (float4*)sH;
        dst[t] = src[t]; dst[t + 512] = src[t + 512];
    }
    __syncthreads();

    const float4* __restrict__ wt4 = (const float4*)WT + oq;   // [k]*64

    float4 acc[8];
#pragma unroll
    for (int rr = 0; rr < 8; ++rr) acc[rr] = make_float4(0.f, 0.f, 0.f, 0.f);

    const int k0 = p * 64;                // this phase's 64-k chunk
    float4 bufA[4], bufB[4];
#pragma unroll
    for (int s = 0; s < 4; ++s) bufA[s] = wt4[(k0 + s) * 64];

    for (int it = 0; it < 8; ++it) {      // 8 k per it
        const int kA = k0 + it * 8, kB = kA + 4;
#pragma unroll
        for (int s = 0; s < 4; ++s) bufB[s] = wt4[(kB + s) * 64];
#pragma unroll
        for (int rr = 0; rr < 8; ++rr) {
            const float4 h4 = *(const float4*)&sH[rr * 512 + kA];  // ds broadcast
            fma4(acc[rr], h4.x, bufA[0]); fma4(acc[rr], h4.y, bufA[1]);
            fma4(acc[rr], h4.z, bufA[2]); fma4(acc[rr], h4.w, bufA[3]);
        }
        if (it < 7) {
#pragma unroll
            for (int s = 0; s < 4; ++s) bufA[s] = wt4[(kA + 8 + s) * 64];
        }
#pragma unroll
        for (int rr = 0; rr < 8; ++rr) {
            const float4 h4 = *(const float4*)&sH[rr * 512 + kB];  // ds broadcast
            fma4(acc[rr], h4.x, bufB[0]); fma4(acc[rr], h4.y, bufB[1]);
            fma4(acc[rr], h4.z, bufB[2]); fma4(acc[rr], h4.w, bufB[3]);
        }
    }

    __syncthreads();                      // sH dead; publish partials
#pragma unroll
    for (int rr = 0; rr < 8; ++rr) sPart[p][rr][oq] = acc[rr];
    __syncthreads();

    const int g = p;                      // final pass: wave = row
    float4 fin = make_float4(0.f, 0.f, 0.f, 0.f);
#pragma unroll
    for (int pp = 0; pp < 8; ++pp) {
        const float4 v = sPart[pp][g][oq];
        fin.x += v.x; fin.y += v.y; fin.z += v.z; fin.w += v.w;
    }

    // Wh: coalesced float4
    ((float4*)(Wh + ((size_t)(b * Nq) + n0 + g) * DOUT))[oq] = fin;

    // WhT[b][o][n0+g]
    float* wT = WhT + (size_t)b * DOUT * Nq;
    wT[(4 * oq + 0) * Nq + n0 + g] = fin.x;
    wT[(4 * oq + 1) * Nq + n0 + g] = fin.y;
    wT[(4 * oq + 2) * Nq + n0 + g] = fin.z;
    wT[(4 * oq + 3) * Nq + n0 + g] = fin.w;

    // r[b][n] = a . Wh[b][n]
    const float4 a4 = ((const float4*)a)[oq];
    float rp = a4.x * fin.x + a4.y * fin.y + a4.z * fin.z + a4.w * fin.w;
#pragma unroll
    for (int off = 32; off > 0; off >>= 1) rp += __shfl_xor(rp, off);
    if ((t & 63) == 0) r[(size_t)b * Nq + n0 + g] = rp;
}

// ---------------------------------------------------------------------------
// K2: e + softmax -> P.  e[i,j] = 0.6(r_i+r_j) + 0.4*sum_o a_o|Wh_io + Wh_jo|
// Block = (b, 8 i-rows), 1024 threads. half = t>>9 owns o-range 128; j = t&511.
// wj stream: coalesced dwords, 16-deep dbuf (registers). a / Wh_i staged in
// LDS once, read as ds_read_b128 broadcasts (NOT global uniform loads).
// ---------------------------------------------------------------------------
__global__ __launch_bounds__(1024, 4) void k2_attn(const float* __restrict__ Wh,
                                                   const float* __restrict__ WhT,
                                                   const float* __restrict__ a,
                                                   const float* __restrict__ r,
                                                   float* __restrict__ P) {
    const int t    = threadIdx.x;
    const int blk  = blockIdx.x;          // 256
    const int b    = blk & 3;
    const int i0   = (blk >> 2) << 3;
    const int half = __builtin_amdgcn_readfirstlane(t >> 9);  // 0/1
    const int j    = t & 511;
    const int obase = half * 128;

    __shared__ float sWi[8 * 256];        // 8 KB  (Wh i-rows)
    __shared__ float sA[256];             // 1 KB
    __shared__ float sAb[8][512];         // 16 KB (half-combine)
    __shared__ float wred[2][8][8];

    {   // one-time stages (coalesced)
        if (t < 512) ((float4*)sWi)[t] = ((const float4*)(Wh + ((size_t)b * Nq + i0) * DOUT))[t];
        else if (t < 576) ((float4*)sA)[t - 512] = ((const float4*)a)[t - 512];
    }
    __syncthreads();

    const float* __restrict__ wj = WhT + (size_t)b * DOUT * Nq + (size_t)obase * Nq + j;
    const float* __restrict__ gr = r + (size_t)b * Nq;

    float ab[8] = {0.f, 0.f, 0.f, 0.f, 0.f, 0.f, 0.f, 0.f};
    float bufA[16], bufB[16];

#pragma unroll
    for (int s = 0; s < 16; ++s) bufA[s] = wj[s * Nq];

    for (int cc = 0; cc < 4; ++cc) {      // 32 o per cc (this half: 128 o)
        const int oA = cc * 32, oB = oA + 16;
#pragma unroll
        for (int s = 0; s < 16; ++s) bufB[s] = wj[(oB + s) * Nq];
#pragma unroll
        for (int grp = 0; grp < 4; ++grp) {
            const int o4 = obase + oA + grp * 4;                      // global o
            const float4 a4 = *(const float4*)&sA[o4];                // ds broadcast
#pragma unroll
            for (int rr = 0; rr < 8; ++rr) {
                const float4 wi4 = *(const float4*)&sWi[rr * 256 + o4]; // ds broadcast
#pragma unroll
                for (int s2 = 0; s2 < 4; ++s2) {
                    const float aq = ((const float*)&a4)[s2];
                    const float wi = ((const float*)&wi4)[s2];
                    ab[rr] = __builtin_fmaf(aq, __builtin_fabsf(wi + bufA[grp * 4 + s2]), ab[rr]);
                }
            }
        }
        if (cc < 3) {
#pragma unroll
            for (int s = 0; s < 16; ++s) bufA[s] = wj[(oA + 32 + s) * Nq];
        }
#pragma unroll
        for (int grp = 0; grp < 4; ++grp) {
            const int o4 = obase + oB + grp * 4;
            const float4 a4 = *(const float4*)&sA[o4];                // ds broadcast
#pragma unroll
            for (int rr = 0; rr < 8; ++rr) {
                const float4 wi4 = *(const float4*)&sWi[rr * 256 + o4]; // ds broadcast
#pragma unroll
                for (int s2 = 0; s2 < 4; ++s2) {
                    const float aq = ((const float*)&a4)[s2];
                    const float wi = ((const float*)&wi4)[s2];
                    ab[rr] = __builtin_fmaf(aq, __builtin_fabsf(wi + bufB[grp * 4 + s2]), ab[rr]);
                }
            }
        }
    }

    // combine the two o-halves
    if (half == 1) {
#pragma unroll
        for (int rr = 0; rr < 8; ++rr) sAb[rr][j] = ab[rr];
    }
    __syncthreads();

    float e[8];
    if (half == 0) {
        const float rj = gr[j];           // coalesced
#pragma unroll
        for (int rr = 0; rr < 8; ++rr) {
            const float abf = ab[rr] + sAb[rr][j];
            e[rr] = 0.6f * (gr[i0 + rr] + rj) + 0.4f * abf;
        }
    }

    const int lane = t & 63;
    const int w    = t >> 6;              // 0..15; half 0 = 0..7

#pragma unroll
    for (int rr = 0; rr < 8; ++rr) {
        float v = (half == 0) ? e[rr] : -1e30f;
#pragma unroll
        for (int off = 32; off > 0; off >>= 1) v = fmaxf(v, __shfl_xor(v, off));
        if (lane == 0 && half == 0) wred[0][rr][w] = v;
    }
    __syncthreads();

    float p[8];
    if (half == 0) {
#pragma unroll
        for (int rr = 0; rr < 8; ++rr) {
            const float4 q0 = *(const float4*)&wred[0][rr][0];
            const float4 q1 = *(const float4*)&wred[0][rr][4];
            const float m = fmaxf(fmaxf(fmaxf(q0.x, q0.y), fmaxf(q0.z, q0.w)),
                                  fmaxf(fmaxf(q1.x, q1.y), fmaxf(q1.z, q1.w)));
            p[rr] = __expf(e[rr] - m);
        }
    }
#pragma unroll
    for (int rr = 0; rr < 8; ++rr) {
        float v = (half == 0) ? p[rr] : 0.f;
#pragma unroll
        for (int off = 32; off > 0; off >>= 1) v += __shfl_xor(v, off);
        if (lane == 0 && half == 0) wred[1][rr][w] = v;
    }
    __syncthreads();

    if (half == 0) {
        float* prow = P + ((size_t)b * Nq + i0) * Nq + j;
#pragma unroll
        for (int rr = 0; rr < 8; ++rr) {
            const float4 q0 = *(const float4*)&wred[1][rr][0];
            const float4 q1 = *(const float4*)&wred[1][rr][4];
            const float s = (q0.x + q0.y + q0.z + q0.w) + (q1.x + q1.y + q1.z + q1.w);
            prow[rr * Nq] = p[rr] * (1.0f / s);   // coalesced
        }
    }
}

// ---------------------------------------------------------------------------
// K3: out = P @ Wh. Mirror of K1: thread = (j-phase, o-quad); Wh stream
// coalesced + dbuf; P rows staged in LDS, read as ds broadcasts; LDS reduce.
// ---------------------------------------------------------------------------
__global__ __launch_bounds__(512, 4) void k3_av(const float* __restrict__ Wh,
                                                const float* __restrict__ P,
                                                float* __restrict__ out) {
    const int t   = threadIdx.x;
    const int blk = blockIdx.x;           // 256
    const int b   = blk & 3;
    const int i0  = (blk >> 2) << 3;
    const int p   = __builtin_amdgcn_readfirstlane(t >> 6);  // j-phase 0..7
    const int oq  = t & 63;               // o-quad

    __shared__ float  sP[8 * 512];        // 16 KB (P rows)
    __shared__ float4 sPart[8][8][64];    // 64 KB

    {   // stage P rows once (coalesced)
        const float4* src = (const float4*)(P + ((size_t)(b * Nq) + i0) * Nq);
        float4* dst = (float4*)sP;
        dst[t] = src[t]; dst[t + 512] = src[t + 512];
    }
    __syncthreads();

    const float4* __restrict__ wh4 = (const float4*)(Wh + (size_t)b * Nq * DOUT) + oq;

    float4 acc[8];
#pragma unroll
    for (int rr = 0; rr < 8; ++rr) acc[rr] = make_float4(0.f, 0.f, 0.f, 0.f);

    const int j0 = p * 64;                // this phase's 64-j chunk
    float4 bufA[4], bufB[4];
#pragma unroll
    for (int s = 0; s < 4; ++s) bufA[s] = wh4[(j0 + s) * 64];

    for (int it = 0; it < 8; ++it) {      // 8 j per it
        const int jA = j0 + it * 8, jB = jA + 4;
#pragma unroll
        for (int s = 0; s < 4; ++s) bufB[s] = wh4[(jB + s) * 64];
#pragma unroll
        for (int rr = 0; rr < 8; ++rr) {
            const float4 p4 = *(const float4*)&sP[rr * 512 + jA];   // ds broadcast
            fma4(acc[rr], p4.x, bufA[0]); fma4(acc[rr], p4.y, bufA[1]);
            fma4(acc[rr], p4.z, bufA[2]); fma4(acc[rr], p4.w, bufA[3]);
        }
        if (it < 7) {
#pragma unroll
            for (int s = 0; s < 4; ++s) bufA[s] = wh4[(jA + 8 + s) * 64];
        }
#pragma unroll
        for (int rr = 0; rr < 8; ++rr) {
            const float4 p4 = *(const float4*)&sP[rr * 512 + jB];   // ds broadcast
            fma4(acc[rr], p4.x, bufB[0]); fma4(acc[rr], p4.y, bufB[1]);
            fma4(acc[rr], p4.z, bufB[2]); fma4(acc[rr], p4.w, bufB[3]);
        }
    }

    __syncthreads();                      // sP dead; publish partials
#pragma unroll
    for (int rr = 0; rr < 8; ++rr) sPart[p][rr][oq] = acc[rr];
    __syncthreads();

    const int g = p;
    float4 fin = make_float4(0.f, 0.f, 0.f, 0.f);
#pragma unroll
    for (int pp = 0; pp < 8; ++pp) {
        const float4 v = sPart[pp][g][oq];
        fin.x += v.x; fin.y += v.y; fin.z += v.z; fin.w += v.w;
    }

    ((float4*)(out + ((size_t)(b * Nq) + i0 + g) * DOUT))[oq] = fin;
}

// ---------------------------------------------------------------------------
extern "C" void kernel_launch(void* const* d_in, const int* in_sizes, int n_in,
                              void* d_out, int out_size, void* d_ws, size_t ws_size,
                              hipStream_t stream) {
    const float* H = (const float*)d_in[0];   // [4,512,512]
    const float* W = (const float*)d_in[1];   // [256,512]
    const float* a = (const float*)d_in[2];   // [256,1]
    float* out = (float*)d_out;               // [4,512,256]

    float* Wh  = (float*)d_ws;                 // 2 MB
    float* WhT = Wh  + Bq * Nq * DOUT;         // 2 MB
    float* P   = WhT + Bq * Nq * DOUT;         // 4 MB
    float* WT  = P;                            // 0.5 MB, dead before K2 writes P
    float* r   = out;                          // 8 KB stash in d_out; K2 reads it
                                               // before K3 overwrites all of out

    hipLaunchKernelGGL(k0_wt,   dim3(16, 8), dim3(32, 8), 0, stream, W, WT);
    hipLaunchKernelGGL(k1_wh,   dim3(256),   dim3(512),   0, stream, H, WT, a, Wh, WhT, r);
    hipLaunchKernelGGL(k2_attn, dim3(256),   dim3(1024),  0, stream, Wh, WhT, a, r, P);
    hipLaunchKernelGGL(k3_av,   dim3(256),   dim3(512),   0, stream, Wh, P, out);
}

// Round 9
// 121.930 us; speedup vs baseline: 1.8080x; 1.8080x over previous
//
#include <hip/hip_runtime.h>

// Problem constants (B=4, N=512, D_in=512, D_out=256), fp32 in/out.
constexpr int Bq   = 4;
constexpr int Nq   = 512;
constexpr int DIN  = 512;
constexpr int DOUT = 256;

__device__ __forceinline__ void fma4(float4& acc, const float s, const float4 v) {
    acc.x = __builtin_fmaf(s, v.x, acc.x);
    acc.y = __builtin_fmaf(s, v.y, acc.y);
    acc.z = __builtin_fmaf(s, v.z, acc.z);
    acc.w = __builtin_fmaf(s, v.w, acc.w);
}

// ---------------------------------------------------------------------------
// K0: WT[k][o] = W[o][k]  (512x256 <- 256x512), LDS tile transpose.
// ---------------------------------------------------------------------------
__global__ __launch_bounds__(256) void k0_wt(const float* __restrict__ W,
                                             float* __restrict__ WT) {
    __shared__ float tile[32][33];
    const int k0 = blockIdx.x * 32;
    const int o0 = blockIdx.y * 32;
    const int tx = threadIdx.x;       // 32
    const int ty = threadIdx.y;       // 8
#pragma unroll
    for (int j = 0; j < 4; ++j)
        tile[ty + 8 * j][tx] = W[(o0 + ty + 8 * j) * DIN + k0 + tx];
    __syncthreads();
#pragma unroll
    for (int j = 0; j < 4; ++j)
        WT[(k0 + ty + 8 * j) * DOUT + o0 + tx] = tile[tx][ty + 8 * j];
}

// ---------------------------------------------------------------------------
// K1: Wh = H @ WT (+ WhT + r = Wh.a). Grid 512 = (b, 4 n-rows), 512 threads
// -> 2 blocks/CU, 4 waves/SIMD (double R7's occupancy). Thread = (k-phase
// p = wave, o-quad oq). WT float4 loaded once per block element (coalesced,
// 4-deep dbuf). H rows staged in LDS once (8 KB), ds broadcasts. Phase
// partials reduced via 32 KB LDS.
// ---------------------------------------------------------------------------
__global__ __launch_bounds__(512, 4) void k1_wh(const float* __restrict__ H,
                                                const float* __restrict__ WT,
                                                const float* __restrict__ a,
                                                float* __restrict__ Wh,
                                                float* __restrict__ WhT,
                                                float* __restrict__ r) {
    const int t   = threadIdx.x;
    const int blk = blockIdx.x;           // 512
    const int b   = blk & 3;              // XCD-swizzled batch
    const int n0  = (blk >> 2) << 2;      // 4 rows per block
    const int p   = __builtin_amdgcn_readfirstlane(t >> 6);  // k-phase 0..7
    const int oq  = t & 63;               // o-quad

    __shared__ float  sH[4 * 512];        // 8 KB (H rows)
    __shared__ float4 sPart[8][4][64];    // 32 KB (phase partials)

    {   // stage H rows once (coalesced): 512 float4 = 2048 floats
        const float4* src = (const float4*)(H + ((size_t)(b * Nq) + n0) * DIN);
        ((float4*)sH)[t] = src[t];
    }
    __syncthreads();

    const float4* __restrict__ wt4 = (const float4*)WT + oq;   // [k]*64

    float4 acc[4];
#pragma unroll
    for (int rr = 0; rr < 4; ++rr) acc[rr] = make_float4(0.f, 0.f, 0.f, 0.f);

    const int k0 = p * 64;                // this phase's 64-k chunk
    float4 bufA[4], bufB[4];
#pragma unroll
    for (int s = 0; s < 4; ++s) bufA[s] = wt4[(k0 + s) * 64];

    for (int it = 0; it < 8; ++it) {      // 8 k per it
        const int kA = k0 + it * 8, kB = kA + 4;
#pragma unroll
        for (int s = 0; s < 4; ++s) bufB[s] = wt4[(kB + s) * 64];
#pragma unroll
        for (int rr = 0; rr < 4; ++rr) {
            const float4 h4 = *(const float4*)&sH[rr * 512 + kA];  // ds broadcast
            fma4(acc[rr], h4.x, bufA[0]); fma4(acc[rr], h4.y, bufA[1]);
            fma4(acc[rr], h4.z, bufA[2]); fma4(acc[rr], h4.w, bufA[3]);
        }
        if (it < 7) {
#pragma unroll
            for (int s = 0; s < 4; ++s) bufA[s] = wt4[(kA + 8 + s) * 64];
        }
#pragma unroll
        for (int rr = 0; rr < 4; ++rr) {
            const float4 h4 = *(const float4*)&sH[rr * 512 + kB];  // ds broadcast
            fma4(acc[rr], h4.x, bufB[0]); fma4(acc[rr], h4.y, bufB[1]);
            fma4(acc[rr], h4.z, bufB[2]); fma4(acc[rr], h4.w, bufB[3]);
        }
    }

#pragma unroll
    for (int rr = 0; rr < 4; ++rr) sPart[p][rr][oq] = acc[rr];
    __syncthreads();

    if (p < 4) {                          // waves 0..3: one row each
        const int g = p;
        float4 fin = make_float4(0.f, 0.f, 0.f, 0.f);
#pragma unroll
        for (int pp = 0; pp < 8; ++pp) {
            const float4 v = sPart[pp][g][oq];
            fin.x += v.x; fin.y += v.y; fin.z += v.z; fin.w += v.w;
        }

        // Wh: coalesced float4
        ((float4*)(Wh + ((size_t)(b * Nq) + n0 + g) * DOUT))[oq] = fin;

        // WhT[b][o][n0+g]
        float* wT = WhT + (size_t)b * DOUT * Nq;
        wT[(4 * oq + 0) * Nq + n0 + g] = fin.x;
        wT[(4 * oq + 1) * Nq + n0 + g] = fin.y;
        wT[(4 * oq + 2) * Nq + n0 + g] = fin.z;
        wT[(4 * oq + 3) * Nq + n0 + g] = fin.w;

        // r[b][n] = a . Wh[b][n]  (wave covers all 256 o of its row)
        const float4 a4 = ((const float4*)a)[oq];
        float rp = a4.x * fin.x + a4.y * fin.y + a4.z * fin.z + a4.w * fin.w;
#pragma unroll
        for (int off = 32; off > 0; off >>= 1) rp += __shfl_xor(rp, off);
        if ((t & 63) == 0) r[(size_t)b * Nq + n0 + g] = rp;
    }
}

// ---------------------------------------------------------------------------
// K2: e + softmax -> P.  e[i,j] = 0.6(r_i+r_j) + 0.4*sum_o a_o|Wh_io + Wh_jo|
// Block = (b, 8 i-rows), 1024 threads. Quarter q = t>>8 owns 64 o; thread
// owns j-PAIR jp = t&255 (float2 stream loads: half the VMEM instrs of R7).
// Uniforms (a, Wh_i, r_i) stay GLOBAL (s_load path — R8 proved LDS-staging
// them spills). Quarters combined via 48 KB LDS; softmax on quarter 0.
// ---------------------------------------------------------------------------
__global__ __launch_bounds__(1024, 4) void k2_attn(const float* __restrict__ Wh,
                                                   const float* __restrict__ WhT,
                                                   const float* __restrict__ a,
                                                   const float* __restrict__ r,
                                                   float* __restrict__ P) {
    const int t   = threadIdx.x;
    const int blk = blockIdx.x;           // 256
    const int b   = blk & 3;
    const int i0  = (blk >> 2) << 3;
    const int q   = __builtin_amdgcn_readfirstlane(t >> 8);   // o-quarter 0..3
    const int jp  = t & 255;              // j-pair {2jp, 2jp+1}
    const int obase = q * 64;

    const float2* __restrict__ wj2 =
        (const float2*)(WhT + (size_t)b * DOUT * Nq + (size_t)obase * Nq) + jp; // +o*256
    const float* __restrict__ gwi = Wh + ((size_t)b * Nq + i0) * DOUT;  // uniform
    const float* __restrict__ gr  = r + (size_t)b * Nq;

    float ab0[8] = {0.f, 0.f, 0.f, 0.f, 0.f, 0.f, 0.f, 0.f};
    float ab1[8] = {0.f, 0.f, 0.f, 0.f, 0.f, 0.f, 0.f, 0.f};
    float2 bufA[8], bufB[8];

#pragma unroll
    for (int s = 0; s < 8; ++s) bufA[s] = wj2[s * 256];

    for (int cc = 0; cc < 4; ++cc) {      // 16 o per cc (quarter: 64 o)
        const int oA = cc * 16, oB = oA + 8;
#pragma unroll
        for (int s = 0; s < 8; ++s) bufB[s] = wj2[(oB + s) * 256];
#pragma unroll
        for (int gg = 0; gg < 2; ++gg) {
            const int o4 = obase + oA + gg * 4;                       // global o
            const float4 a4 = *(const float4*)(a + o4);               // s_load
#pragma unroll
            for (int rr = 0; rr < 8; ++rr) {
                const float4 wi4 = *(const float4*)(gwi + rr * DOUT + o4); // s_load
#pragma unroll
                for (int s2 = 0; s2 < 4; ++s2) {
                    const float aq = ((const float*)&a4)[s2];
                    const float wi = ((const float*)&wi4)[s2];
                    const float2 wv = bufA[gg * 4 + s2];
                    ab0[rr] = __builtin_fmaf(aq, __builtin_fabsf(wi + wv.x), ab0[rr]);
                    ab1[rr] = __builtin_fmaf(aq, __builtin_fabsf(wi + wv.y), ab1[rr]);
                }
            }
        }
        if (cc < 3) {
#pragma unroll
            for (int s = 0; s < 8; ++s) bufA[s] = wj2[(oA + 16 + s) * 256];
        }
#pragma unroll
        for (int gg = 0; gg < 2; ++gg) {
            const int o4 = obase + oB + gg * 4;
            const float4 a4 = *(const float4*)(a + o4);               // s_load
#pragma unroll
            for (int rr = 0; rr < 8; ++rr) {
                const float4 wi4 = *(const float4*)(gwi + rr * DOUT + o4); // s_load
#pragma unroll
                for (int s2 = 0; s2 < 4; ++s2) {
                    const float aq = ((const float*)&a4)[s2];
                    const float wi = ((const float*)&wi4)[s2];
                    const float2 wv = bufB[gg * 4 + s2];
                    ab0[rr] = __builtin_fmaf(aq, __builtin_fabsf(wi + wv.x), ab0[rr]);
                    ab1[rr] = __builtin_fmaf(aq, __builtin_fabsf(wi + wv.y), ab1[rr]);
                }
            }
        }
    }

    // combine quarters 1..3 into quarter 0 via LDS
    __shared__ float sAb[3][8][512];      // 48 KB
    __shared__ float wred[2][8][4];
    if (q > 0) {
#pragma unroll
        for (int rr = 0; rr < 8; ++rr)
            ((float2*)&sAb[q - 1][rr][0])[jp] = make_float2(ab0[rr], ab1[rr]);
    }
    __syncthreads();

    float e0[8], e1[8];
    if (q == 0) {
        const float2 rj2 = ((const float2*)gr)[jp];   // coalesced
#pragma unroll
        for (int rr = 0; rr < 8; ++rr) {
            const float2 x0 = ((const float2*)&sAb[0][rr][0])[jp];
            const float2 x1 = ((const float2*)&sAb[1][rr][0])[jp];
            const float2 x2 = ((const float2*)&sAb[2][rr][0])[jp];
            const float A0 = ab0[rr] + x0.x + x1.x + x2.x;
            const float A1 = ab1[rr] + x0.y + x1.y + x2.y;
            const float ri = gr[i0 + rr];             // s_load
            e0[rr] = 0.6f * (ri + rj2.x) + 0.4f * A0;
            e1[rr] = 0.6f * (ri + rj2.y) + 0.4f * A1;
        }
    }

    const int lane = t & 63;
    const int w    = (t >> 6) & 3;        // wave within quarter

#pragma unroll
    for (int rr = 0; rr < 8; ++rr) {
        float v = (q == 0) ? fmaxf(e0[rr], e1[rr]) : -3e38f;
#pragma unroll
        for (int off = 32; off > 0; off >>= 1) v = fmaxf(v, __shfl_xor(v, off));
        if (lane == 0 && q == 0) wred[0][rr][w] = v;
    }
    __syncthreads();

    float p0[8], p1[8];
    if (q == 0) {
#pragma unroll
        for (int rr = 0; rr < 8; ++rr) {
            const float4 qv = *(const float4*)&wred[0][rr][0];
            const float m = fmaxf(fmaxf(qv.x, qv.y), fmaxf(qv.z, qv.w));
            p0[rr] = __expf(e0[rr] - m);
            p1[rr] = __expf(e1[rr] - m);
        }
    }
#pragma unroll
    for (int rr = 0; rr < 8; ++rr) {
        float v = (q == 0) ? (p0[rr] + p1[rr]) : 0.f;
#pragma unroll
        for (int off = 32; off > 0; off >>= 1) v += __shfl_xor(v, off);
        if (lane == 0 && q == 0) wred[1][rr][w] = v;
    }
    __syncthreads();

    if (q == 0) {
        float2* prow = (float2*)(P + ((size_t)b * Nq + i0) * Nq) + jp;
#pragma unroll
        for (int rr = 0; rr < 8; ++rr) {
            const float4 qv = *(const float4*)&wred[1][rr][0];
            const float inv = 1.0f / (qv.x + qv.y + qv.z + qv.w);
            prow[rr * 256] = make_float2(p0[rr] * inv, p1[rr] * inv);  // coalesced
        }
    }
}

// ---------------------------------------------------------------------------
// K3: out = P @ Wh. Mirror of K1: grid 512 = (b, 4 i-rows), 512 threads.
// Thread = (j-phase, o-quad); Wh stream coalesced + dbuf; P rows staged in
// LDS (8 KB), ds broadcasts; 32 KB LDS partial reduce.
// ---------------------------------------------------------------------------
__global__ __launch_bounds__(512, 4) void k3_av(const float* __restrict__ Wh,
                                                const float* __restrict__ P,
                                                float* __restrict__ out) {
    const int t   = threadIdx.x;
    const int blk = blockIdx.x;           // 512
    const int b   = blk & 3;
    const int i0  = (blk >> 2) << 2;      // 4 rows per block
    const int p   = __builtin_amdgcn_readfirstlane(t >> 6);  // j-phase 0..7
    const int oq  = t & 63;               // o-quad

    __shared__ float  sP[4 * 512];        // 8 KB (P rows)
    __shared__ float4 sPart[8][4][64];    // 32 KB

    {   // stage P rows once (coalesced): 512 float4
        const float4* src = (const float4*)(P + ((size_t)(b * Nq) + i0) * Nq);
        ((float4*)sP)[t] = src[t];
    }
    __syncthreads();

    const float4* __restrict__ wh4 = (const float4*)(Wh + (size_t)b * Nq * DOUT) + oq;

    float4 acc[4];
#pragma unroll
    for (int rr = 0; rr < 4; ++rr) acc[rr] = make_float4(0.f, 0.f, 0.f, 0.f);

    const int j0 = p * 64;                // this phase's 64-j chunk
    float4 bufA[4], bufB[4];
#pragma unroll
    for (int s = 0; s < 4; ++s) bufA[s] = wh4[(j0 + s) * 64];

    for (int it = 0; it < 8; ++it) {      // 8 j per it
        const int jA = j0 + it * 8, jB = jA + 4;
#pragma unroll
        for (int s = 0; s < 4; ++s) bufB[s] = wh4[(jB + s) * 64];
#pragma unroll
        for (int rr = 0; rr < 4; ++rr) {
            const float4 p4 = *(const float4*)&sP[rr * 512 + jA];   // ds broadcast
            fma4(acc[rr], p4.x, bufA[0]); fma4(acc[rr], p4.y, bufA[1]);
            fma4(acc[rr], p4.z, bufA[2]); fma4(acc[rr], p4.w, bufA[3]);
        }
        if (it < 7) {
#pragma unroll
            for (int s = 0; s < 4; ++s) bufA[s] = wh4[(jA + 8 + s) * 64];
        }
#pragma unroll
        for (int rr = 0; rr < 4; ++rr) {
            const float4 p4 = *(const float4*)&sP[rr * 512 + jB];   // ds broadcast
            fma4(acc[rr], p4.x, bufB[0]); fma4(acc[rr], p4.y, bufB[1]);
            fma4(acc[rr], p4.z, bufB[2]); fma4(acc[rr], p4.w, bufB[3]);
        }
    }

#pragma unroll
    for (int rr = 0; rr < 4; ++rr) sPart[p][rr][oq] = acc[rr];
    __syncthreads();

    if (p < 4) {
        const int g = p;
        float4 fin = make_float4(0.f, 0.f, 0.f, 0.f);
#pragma unroll
        for (int pp = 0; pp < 8; ++pp) {
            const float4 v = sPart[pp][g][oq];
            fin.x += v.x; fin.y += v.y; fin.z += v.z; fin.w += v.w;
        }
        ((float4*)(out + ((size_t)(b * Nq) + i0 + g) * DOUT))[oq] = fin;
    }
}

// ---------------------------------------------------------------------------
extern "C" void kernel_launch(void* const* d_in, const int* in_sizes, int n_in,
                              void* d_out, int out_size, void* d_ws, size_t ws_size,
                              hipStream_t stream) {
    const float* H = (const float*)d_in[0];   // [4,512,512]
    const float* W = (const float*)d_in[1];   // [256,512]
    const float* a = (const float*)d_in[2];   // [256,1]
    float* out = (float*)d_out;               // [4,512,256]

    float* Wh  = (float*)d_ws;                 // 2 MB
    float* WhT = Wh  + Bq * Nq * DOUT;         // 2 MB
    float* P   = WhT + Bq * Nq * DOUT;         // 4 MB
    float* WT  = P;                            // 0.5 MB, dead before K2 writes P
    float* r   = out;                          // 8 KB stash in d_out; K2 reads it
                                               // before K3 overwrites all of out

    hipLaunchKernelGGL(k0_wt,   dim3(16, 8), dim3(32, 8), 0, stream, W, WT);
    hipLaunchKernelGGL(k1_wh,   dim3(512),   dim3(512),   0, stream, H, WT, a, Wh, WhT, r);
    hipLaunchKernelGGL(k2_attn, dim3(256),   dim3(1024),  0, stream, Wh, WhT, a, r, P);
    hipLaunchKernelGGL(k3_av,   dim3(512),   dim3(512),   0, stream, Wh, P, out);
}

// Round 10
// 115.450 us; speedup vs baseline: 1.9094x; 1.0561x over previous
//
#include <hip/hip_runtime.h>

// Problem constants (B=4, N=512, D_in=512, D_out=256), fp32 in/out.
constexpr int Bq   = 4;
constexpr int Nq   = 512;
constexpr int DIN  = 512;
constexpr int DOUT = 256;

typedef float v2f __attribute__((ext_vector_type(2)));
typedef float v4f __attribute__((ext_vector_type(4)));

__device__ __forceinline__ v4f fma4v(const float s, const v4f v, const v4f acc) {
    v4f sv = s;                                   // splat
    return __builtin_elementwise_fma(sv, v, acc); // -> 2x v_pk_fma_f32
}

// ---------------------------------------------------------------------------
// K0: WT[k][o] = W[o][k]  (512x256 <- 256x512), LDS tile transpose.
// ---------------------------------------------------------------------------
__global__ __launch_bounds__(256) void k0_wt(const float* __restrict__ W,
                                             float* __restrict__ WT) {
    __shared__ float tile[32][33];
    const int k0 = blockIdx.x * 32;
    const int o0 = blockIdx.y * 32;
    const int tx = threadIdx.x;       // 32
    const int ty = threadIdx.y;       // 8
#pragma unroll
    for (int j = 0; j < 4; ++j)
        tile[ty + 8 * j][tx] = W[(o0 + ty + 8 * j) * DIN + k0 + tx];
    __syncthreads();
#pragma unroll
    for (int j = 0; j < 4; ++j)
        WT[(k0 + ty + 8 * j) * DOUT + o0 + tx] = tile[tx][ty + 8 * j];
}

// ---------------------------------------------------------------------------
// K1: Wh = H @ WT (+ WhT + r = Wh.a). Grid 512 = (b, 4 n-rows), 512 threads.
// Structure = R9 (proven); inner fma now packed (v4f elementwise fma).
// ---------------------------------------------------------------------------
__global__ __launch_bounds__(512, 4) void k1_wh(const float* __restrict__ H,
                                                const float* __restrict__ WT,
                                                const float* __restrict__ a,
                                                float* __restrict__ Wh,
                                                float* __restrict__ WhT,
                                                float* __restrict__ r) {
    const int t   = threadIdx.x;
    const int blk = blockIdx.x;           // 512
    const int b   = blk & 3;              // XCD-swizzled batch
    const int n0  = (blk >> 2) << 2;      // 4 rows per block
    const int p   = __builtin_amdgcn_readfirstlane(t >> 6);  // k-phase 0..7
    const int oq  = t & 63;               // o-quad

    __shared__ float sH[4 * 512];         // 8 KB (H rows)
    __shared__ v4f   sPart[8][4][64];     // 32 KB (phase partials)

    {   // stage H rows once (coalesced): 512 float4
        const v4f* src = (const v4f*)(H + ((size_t)(b * Nq) + n0) * DIN);
        ((v4f*)sH)[t] = src[t];
    }
    __syncthreads();

    const v4f* __restrict__ wt4 = (const v4f*)WT + oq;   // [k]*64

    v4f acc[4];
#pragma unroll
    for (int rr = 0; rr < 4; ++rr) acc[rr] = (v4f)0.f;

    const int k0 = p * 64;                // this phase's 64-k chunk
    v4f bufA[4], bufB[4];
#pragma unroll
    for (int s = 0; s < 4; ++s) bufA[s] = wt4[(k0 + s) * 64];

    for (int it = 0; it < 8; ++it) {      // 8 k per it
        const int kA = k0 + it * 8, kB = kA + 4;
#pragma unroll
        for (int s = 0; s < 4; ++s) bufB[s] = wt4[(kB + s) * 64];
#pragma unroll
        for (int rr = 0; rr < 4; ++rr) {
            const v4f h4 = *(const v4f*)&sH[rr * 512 + kA];  // ds broadcast
            acc[rr] = fma4v(h4.x, bufA[0], acc[rr]);
            acc[rr] = fma4v(h4.y, bufA[1], acc[rr]);
            acc[rr] = fma4v(h4.z, bufA[2], acc[rr]);
            acc[rr] = fma4v(h4.w, bufA[3], acc[rr]);
        }
        if (it < 7) {
#pragma unroll
            for (int s = 0; s < 4; ++s) bufA[s] = wt4[(kA + 8 + s) * 64];
        }
#pragma unroll
        for (int rr = 0; rr < 4; ++rr) {
            const v4f h4 = *(const v4f*)&sH[rr * 512 + kB];  // ds broadcast
            acc[rr] = fma4v(h4.x, bufB[0], acc[rr]);
            acc[rr] = fma4v(h4.y, bufB[1], acc[rr]);
            acc[rr] = fma4v(h4.z, bufB[2], acc[rr]);
            acc[rr] = fma4v(h4.w, bufB[3], acc[rr]);
        }
    }

#pragma unroll
    for (int rr = 0; rr < 4; ++rr) sPart[p][rr][oq] = acc[rr];
    __syncthreads();

    if (p < 4) {                          // waves 0..3: one row each
        const int g = p;
        v4f fin = (v4f)0.f;
#pragma unroll
        for (int pp = 0; pp < 8; ++pp) fin += sPart[pp][g][oq];

        ((v4f*)(Wh + ((size_t)(b * Nq) + n0 + g) * DOUT))[oq] = fin;

        float* wT = WhT + (size_t)b * DOUT * Nq;
        wT[(4 * oq + 0) * Nq + n0 + g] = fin.x;
        wT[(4 * oq + 1) * Nq + n0 + g] = fin.y;
        wT[(4 * oq + 2) * Nq + n0 + g] = fin.z;
        wT[(4 * oq + 3) * Nq + n0 + g] = fin.w;

        const v4f a4 = ((const v4f*)a)[oq];
        float rp = a4.x * fin.x + a4.y * fin.y + a4.z * fin.z + a4.w * fin.w;
#pragma unroll
        for (int off = 32; off > 0; off >>= 1) rp += __shfl_xor(rp, off);
        if ((t & 63) == 0) r[(size_t)b * Nq + n0 + g] = rp;
    }
}

// ---------------------------------------------------------------------------
// K23: fused e+softmax (phase A, R9-K2 shape) and out = P @ Wh (phase B).
// Block = (b, 8 i-rows), 1024 threads. P never touches global (lives in sP).
// Phase A inner uses packed v2f ops: pk_add + pk_max(w,-w) + pk_fma.
// LDS: 32 KB arena (sAb in A, sPart in B) + 16 KB sP + small wred = ~48 KB.
// ---------------------------------------------------------------------------
__global__ __launch_bounds__(1024, 4) void k23(const float* __restrict__ Wh,
                                               const float* __restrict__ WhT,
                                               const float* __restrict__ a,
                                               const float* __restrict__ r,
                                               float* __restrict__ out) {
    const int t   = threadIdx.x;
    const int blk = blockIdx.x;           // 256
    const int b   = blk & 3;
    const int i0  = (blk >> 2) << 3;

    __shared__ float smem[8192];          // 32 KB arena: sAb (A) / sPart (B)
    __shared__ float sP[8 * 512];         // 16 KB (normalized P)
    __shared__ float wred[2][8][4];

    // ======================= Phase A: e + softmax -> sP ====================
    {
        const int q  = __builtin_amdgcn_readfirstlane(t >> 8);  // o-quarter
        const int jp = t & 255;            // j-pair {2jp, 2jp+1}
        const int obase = q * 64;

        const v2f* __restrict__ wj2 =
            (const v2f*)(WhT + (size_t)b * DOUT * Nq + (size_t)obase * Nq) + jp;
        const float* __restrict__ gwi = Wh + ((size_t)b * Nq + i0) * DOUT; // uniform
        const float* __restrict__ gr  = r + (size_t)b * Nq;

        v2f ab[8];
#pragma unroll
        for (int rr = 0; rr < 8; ++rr) ab[rr] = (v2f)0.f;
        v2f bufA[8], bufB[8];

#pragma unroll
        for (int s = 0; s < 8; ++s) bufA[s] = wj2[s * 256];

        for (int cc = 0; cc < 4; ++cc) {   // 16 o per cc (quarter: 64 o)
            const int oA = cc * 16, oB = oA + 8;
#pragma unroll
            for (int s = 0; s < 8; ++s) bufB[s] = wj2[(oB + s) * 256];
#pragma unroll
            for (int gg = 0; gg < 2; ++gg) {
                const int o4 = obase + oA + gg * 4;
                const float4 a4 = *(const float4*)(a + o4);               // s_load
#pragma unroll
                for (int rr = 0; rr < 8; ++rr) {
                    const float4 wi4 = *(const float4*)(gwi + rr * DOUT + o4); // s_load
#pragma unroll
                    for (int s2 = 0; s2 < 4; ++s2) {
                        const float aq = ((const float*)&a4)[s2];
                        const float wi = ((const float*)&wi4)[s2];
                        v2f w  = bufA[gg * 4 + s2] + wi;                  // pk_add
                        v2f aw = __builtin_elementwise_max(w, -w);        // pk_max
                        v2f av = aq;
                        ab[rr] = __builtin_elementwise_fma(av, aw, ab[rr]); // pk_fma
                    }
                }
            }
            if (cc < 3) {
#pragma unroll
                for (int s = 0; s < 8; ++s) bufA[s] = wj2[(oA + 16 + s) * 256];
            }
#pragma unroll
            for (int gg = 0; gg < 2; ++gg) {
                const int o4 = obase + oB + gg * 4;
                const float4 a4 = *(const float4*)(a + o4);               // s_load
#pragma unroll
                for (int rr = 0; rr < 8; ++rr) {
                    const float4 wi4 = *(const float4*)(gwi + rr * DOUT + o4); // s_load
#pragma unroll
                    for (int s2 = 0; s2 < 4; ++s2) {
                        const float aq = ((const float*)&a4)[s2];
                        const float wi = ((const float*)&wi4)[s2];
                        v2f w  = bufB[gg * 4 + s2] + wi;
                        v2f aw = __builtin_elementwise_max(w, -w);
                        v2f av = aq;
                        ab[rr] = __builtin_elementwise_fma(av, aw, ab[rr]);
                    }
                }
            }
        }

        // two-step quarter combine in the 32 KB arena: sAb[2][8][512]
        v2f* sAb = (v2f*)smem;             // [g][rr][jp] as v2f: (g*8+rr)*256+jp
        if (q >= 2) {
#pragma unroll
            for (int rr = 0; rr < 8; ++rr) sAb[((q - 2) * 8 + rr) * 256 + jp] = ab[rr];
        }
        __syncthreads();
        if (q < 2) {
#pragma unroll
            for (int rr = 0; rr < 8; ++rr) ab[rr] += sAb[(q * 8 + rr) * 256 + jp];
        }
        __syncthreads();
        if (q == 1) {
#pragma unroll
            for (int rr = 0; rr < 8; ++rr) sAb[(0 * 8 + rr) * 256 + jp] = ab[rr];
        }
        __syncthreads();

        float e0[8], e1[8];
        if (q == 0) {
            const v2f rj2 = ((const v2f*)gr)[jp];   // coalesced
#pragma unroll
            for (int rr = 0; rr < 8; ++rr) {
                const v2f x = sAb[(0 * 8 + rr) * 256 + jp];
                const float A0 = ab[rr].x + x.x;
                const float A1 = ab[rr].y + x.y;
                const float ri = gr[i0 + rr];       // s_load
                e0[rr] = 0.6f * (ri + rj2.x) + 0.4f * A0;
                e1[rr] = 0.6f * (ri + rj2.y) + 0.4f * A1;
            }
        }

        const int lane = t & 63;
        const int w    = (t >> 6) & 3;     // wave within quarter

#pragma unroll
        for (int rr = 0; rr < 8; ++rr) {
            float v = (q == 0) ? fmaxf(e0[rr], e1[rr]) : -3e38f;
#pragma unroll
            for (int off = 32; off > 0; off >>= 1) v = fmaxf(v, __shfl_xor(v, off));
            if (lane == 0 && q == 0) wred[0][rr][w] = v;
        }
        __syncthreads();

        float p0[8], p1[8];
        if (q == 0) {
#pragma unroll
            for (int rr = 0; rr < 8; ++rr) {
                const float4 qv = *(const float4*)&wred[0][rr][0];
                const float m = fmaxf(fmaxf(qv.x, qv.y), fmaxf(qv.z, qv.w));
                p0[rr] = __expf(e0[rr] - m);
                p1[rr] = __expf(e1[rr] - m);
            }
        }
#pragma unroll
        for (int rr = 0; rr < 8; ++rr) {
            float v = (q == 0) ? (p0[rr] + p1[rr]) : 0.f;
#pragma unroll
            for (int off = 32; off > 0; off >>= 1) v += __shfl_xor(v, off);
            if (lane == 0 && q == 0) wred[1][rr][w] = v;
        }
        __syncthreads();

        if (q == 0) {
#pragma unroll
            for (int rr = 0; rr < 8; ++rr) {
                const float4 qv = *(const float4*)&wred[1][rr][0];
                const float inv = 1.0f / (qv.x + qv.y + qv.z + qv.w);
                ((v2f*)sP)[rr * 256 + jp] = (v2f){p0[rr] * inv, p1[rr] * inv};
            }
        }
        __syncthreads();                  // sP ready; arena free for phase B
    }

    // ======================= Phase B: out = P @ Wh =========================
    {
        const int p2 = __builtin_amdgcn_readfirstlane(t >> 6);  // 0..15
        const int jh = p2 & 7;            // j-octant (64 j)
        const int rh = p2 >> 3;           // row-half (rows rh*4..rh*4+3)
        const int oq = t & 63;            // o-quad

        const v4f* __restrict__ wh4 = (const v4f*)(Wh + (size_t)b * Nq * DOUT) + oq;

        v4f acc[4];
#pragma unroll
        for (int rr = 0; rr < 4; ++rr) acc[rr] = (v4f)0.f;

        const int j0 = jh * 64;
        v4f bufA[4], bufB[4];
#pragma unroll
        for (int s = 0; s < 4; ++s) bufA[s] = wh4[(j0 + s) * 64];

        for (int it = 0; it < 8; ++it) {  // 8 j per it
            const int jA = j0 + it * 8, jB = jA + 4;
#pragma unroll
            for (int s = 0; s < 4; ++s) bufB[s] = wh4[(jB + s) * 64];
#pragma unroll
            for (int rr = 0; rr < 4; ++rr) {
                const v4f p4 = *(const v4f*)&sP[(rh * 4 + rr) * 512 + jA];  // ds bcast
                acc[rr] = fma4v(p4.x, bufA[0], acc[rr]);
                acc[rr] = fma4v(p4.y, bufA[1], acc[rr]);
                acc[rr] = fma4v(p4.z, bufA[2], acc[rr]);
                acc[rr] = fma4v(p4.w, bufA[3], acc[rr]);
            }
            if (it < 7) {
#pragma unroll
                for (int s = 0; s < 4; ++s) bufA[s] = wh4[(jA + 8 + s) * 64];
            }
#pragma unroll
            for (int rr = 0; rr < 4; ++rr) {
                const v4f p4 = *(const v4f*)&sP[(rh * 4 + rr) * 512 + jB];  // ds bcast
                acc[rr] = fma4v(p4.x, bufB[0], acc[rr]);
                acc[rr] = fma4v(p4.y, bufB[1], acc[rr]);
                acc[rr] = fma4v(p4.z, bufB[2], acc[rr]);
                acc[rr] = fma4v(p4.w, bufB[3], acc[rr]);
            }
        }

        // two-step j-octant reduce in the 32 KB arena: sPart[4][8][64] v4f
        v4f* sPart = (v4f*)smem;
        if (jh < 4) {
#pragma unroll
            for (int rr = 0; rr < 4; ++rr)
                sPart[(jh * 8 + rh * 4 + rr) * 64 + oq] = acc[rr];
        }
        __syncthreads();
        if (jh >= 4) {
#pragma unroll
            for (int rr = 0; rr < 4; ++rr)
                sPart[((jh - 4) * 8 + rh * 4 + rr) * 64 + oq] += acc[rr];
        }
        __syncthreads();

        if (p2 < 8) {                     // waves 0..7: one row each
            const int row = p2;
            v4f fin = sPart[(0 * 8 + row) * 64 + oq] + sPart[(1 * 8 + row) * 64 + oq]
                    + sPart[(2 * 8 + row) * 64 + oq] + sPart[(3 * 8 + row) * 64 + oq];
            ((v4f*)(out + ((size_t)(b * Nq) + i0 + row) * DOUT))[oq] = fin;
        }
    }
}

// ---------------------------------------------------------------------------
extern "C" void kernel_launch(void* const* d_in, const int* in_sizes, int n_in,
                              void* d_out, int out_size, void* d_ws, size_t ws_size,
                              hipStream_t stream) {
    const float* H = (const float*)d_in[0];   // [4,512,512]
    const float* W = (const float*)d_in[1];   // [256,512]
    const float* a = (const float*)d_in[2];   // [256,1]
    float* out = (float*)d_out;               // [4,512,256]

    float* Wh  = (float*)d_ws;                 // 2 MB
    float* WhT = Wh  + Bq * Nq * DOUT;         // 2 MB
    float* r   = WhT + Bq * Nq * DOUT;         // 8 KB (moved off d_out: k23
                                               //  writes out while others read r)
    float* WT  = r   + Bq * Nq;                // 0.5 MB

    hipLaunchKernelGGL(k0_wt, dim3(16, 8), dim3(32, 8), 0, stream, W, WT);
    hipLaunchKernelGGL(k1_wh, dim3(512),   dim3(512),   0, stream, H, WT, a, Wh, WhT, r);
    hipLaunchKernelGGL(k23,   dim3(256),   dim3(1024),  0, stream, Wh, WhT, a, r, out);
}